// Round 1
// baseline (427.472 us; speedup 1.0000x reference)
//
#include <hip/hip_runtime.h>

// QuantizedLinear: out[M,N] = (rowquant(x) . W_q) * a_scale[M] * w_scale[N] + bias[N]
// M=8192, K=4096, N=4096.  Three kernels:
//  1) quant_kernel:       per-row absmax -> a_scale, x_q int8 [M,K]
//  2) transpose_pack:     W_q int32 [K,N] -> int8 [N,K] (k-contiguous for MFMA B)
//  3) gemm_i8_kernel:     m97-style 128x128x64 tile, mfma_i32_16x16x64_i8

typedef int int32x4 __attribute__((ext_vector_type(4)));

#define TILE_BM 128
#define TILE_BN 128
#define TILE_BK 64

__device__ __forceinline__ void async_copy16(const void* g, void* l) {
    __builtin_amdgcn_global_load_lds(
        (const __attribute__((address_space(1))) unsigned int*)g,
        (__attribute__((address_space(3))) unsigned int*)l,
        16, 0, 0);
}

__device__ __forceinline__ int quant1(float x, float s) {
    float q = rintf(x / s);               // true division: bit-match np (x / a_scale)
    q = fminf(127.0f, fmaxf(-128.0f, q)); // np.clip(round, -128, 127)
    return (int)q;
}

// ---------------- kernel 1: per-row dynamic quantization ----------------
// grid = M blocks, 256 threads; K must be 4096 (16 floats per thread).
__global__ __launch_bounds__(256) void quant_kernel(
    const float* __restrict__ x, signed char* __restrict__ xq,
    float* __restrict__ ascale, int K)
{
    const int row = blockIdx.x;
    const int t = threadIdx.x;
    const float4* xr4 = (const float4*)(x + (size_t)row * K);

    float4 v[4];
    float mx = 0.0f;
#pragma unroll
    for (int i = 0; i < 4; ++i) {
        v[i] = xr4[t * 4 + i];
        mx = fmaxf(mx, fmaxf(fmaxf(fabsf(v[i].x), fabsf(v[i].y)),
                             fmaxf(fabsf(v[i].z), fabsf(v[i].w))));
    }
    // wave-64 butterfly max
#pragma unroll
    for (int off = 32; off > 0; off >>= 1)
        mx = fmaxf(mx, __shfl_xor(mx, off, 64));
    __shared__ float wmax[4];
    if ((t & 63) == 0) wmax[t >> 6] = mx;
    __syncthreads();
    mx = fmaxf(fmaxf(wmax[0], wmax[1]), fmaxf(wmax[2], wmax[3]));

    const float s = fmaxf(mx / 127.0f, 1e-8f);
    if (t == 0) ascale[row] = s;

    int out[4];
#pragma unroll
    for (int i = 0; i < 4; ++i) {
        const int b0 = quant1(v[i].x, s);
        const int b1 = quant1(v[i].y, s);
        const int b2 = quant1(v[i].z, s);
        const int b3 = quant1(v[i].w, s);
        out[i] = (b0 & 255) | ((b1 & 255) << 8) | ((b2 & 255) << 16) | ((b3 & 255) << 24);
    }
    *(int32x4*)(xq + (size_t)row * K + t * 16) = *(const int32x4*)out;
}

// ---------------- kernel 2: transpose + pack weight ----------------
// W_q arrives as int32 [K,N]; produce int8 [N,K].
// grid = (N/64, K/64), 256 threads. 64x64 element tile via dword LDS.
__global__ __launch_bounds__(256) void transpose_pack_kernel(
    const int* __restrict__ Bq, signed char* __restrict__ Bt, int K, int N)
{
    __shared__ int lds[64 * 17]; // [n_local 0..63][k-dword 0..15] + pad
    const int t = threadIdx.x;
    const int n0 = blockIdx.x * 64;
    const int k0 = blockIdx.y * 64;

    const int r = t >> 4;            // k-dword index 0..15 -> k rows 4r..4r+3
    const int ncol = (t & 15) * 4;   // n offset 0,4,...,60

    const int* src = Bq + (size_t)(k0 + 4 * r) * N + n0 + ncol;
    const int4 u0 = *(const int4*)(src);
    const int4 u1 = *(const int4*)(src + N);
    const int4 u2 = *(const int4*)(src + 2 * (size_t)N);
    const int4 u3 = *(const int4*)(src + 3 * (size_t)N);

    lds[(ncol + 0) * 17 + r] = (u0.x & 255) | ((u1.x & 255) << 8) | ((u2.x & 255) << 16) | ((u3.x & 255) << 24);
    lds[(ncol + 1) * 17 + r] = (u0.y & 255) | ((u1.y & 255) << 8) | ((u2.y & 255) << 16) | ((u3.y & 255) << 24);
    lds[(ncol + 2) * 17 + r] = (u0.z & 255) | ((u1.z & 255) << 8) | ((u2.z & 255) << 16) | ((u3.z & 255) << 24);
    lds[(ncol + 3) * 17 + r] = (u0.w & 255) | ((u1.w & 255) << 8) | ((u2.w & 255) << 16) | ((u3.w & 255) << 24);
    __syncthreads();

    const int nl = t >> 2, ch = t & 3;
    int o[4];
#pragma unroll
    for (int i = 0; i < 4; ++i) o[i] = lds[nl * 17 + ch * 4 + i];
    *(int32x4*)(Bt + (size_t)(n0 + nl) * K + k0 + ch * 16) = *(const int32x4*)o;
}

// ---------------- kernel 3: int8 GEMM + dequant epilogue ----------------
// A = x_q [M,K] int8, B = Bt [N,K] int8 (k-contiguous). 128x128 C-tile/block,
// BK=64. 4 waves in 2x2; each wave 64x64 via 4x4 grid of 16x16x64 MFMAs.
__global__ __launch_bounds__(256, 2) void gemm_i8_kernel(
    const signed char* __restrict__ Aq, const signed char* __restrict__ Bt,
    const float* __restrict__ ascale, const float* __restrict__ wscale,
    const float* __restrict__ bias, float* __restrict__ C,
    int M, int N, int K)
{
    __shared__ __align__(16) signed char As[TILE_BM * TILE_BK]; // 8 KB, row-major [128][64], unpadded (global_load_lds layout)
    __shared__ __align__(16) signed char Bs[TILE_BN * TILE_BK]; // 8 KB, [n][k]

    const int t = threadIdx.x;
    const int lane = t & 63;
    const int w = t >> 6;
    const int wr = w >> 1, wc = w & 1;

    const int m0 = blockIdx.y * TILE_BM;
    const int n0 = blockIdx.x * TILE_BN;

    // staging: chunk ci = t (rows 0..63) and ci = t+256 (rows 64..127); 16 B each
    const int srow = t >> 2;
    const int schunk = (t & 3) * 16;
    const signed char* gA0 = Aq + (size_t)(m0 + srow) * K + schunk;
    const signed char* gA1 = gA0 + (size_t)64 * K;
    const signed char* gB0 = Bt + (size_t)(n0 + srow) * K + schunk;
    const signed char* gB1 = gB0 + (size_t)64 * K;
    signed char* lA0 = As + t * 16;
    signed char* lA1 = lA0 + 4096;
    signed char* lB0 = Bs + t * 16;
    signed char* lB1 = lB0 + 4096;

    // fragment read bases: A[m=lane&15][k=(lane>>4)*16 + j]
    const int kb16 = (lane >> 4) * 16;
    const int ml = lane & 15;
    const signed char* fA = As + (wr * 64 + ml) * TILE_BK + kb16;
    const signed char* fB = Bs + (wc * 64 + ml) * TILE_BK + kb16;

    int32x4 acc[4][4] = {};

    for (int k0 = 0; k0 < K; k0 += TILE_BK) {
        async_copy16(gA0 + k0, lA0);
        async_copy16(gA1 + k0, lA1);
        async_copy16(gB0 + k0, lB0);
        async_copy16(gB1 + k0, lB1);
        __syncthreads(); // drains vmcnt -> LDS tiles complete

        int32x4 af[4], bf[4];
#pragma unroll
        for (int i = 0; i < 4; ++i) {
            af[i] = *(const int32x4*)(fA + i * 16 * TILE_BK);
            bf[i] = *(const int32x4*)(fB + i * 16 * TILE_BK);
        }
#pragma unroll
        for (int i = 0; i < 4; ++i)
#pragma unroll
            for (int j = 0; j < 4; ++j)
                acc[i][j] = __builtin_amdgcn_mfma_i32_16x16x64_i8(af[i], bf[j], acc[i][j], 0, 0, 0);
        __syncthreads(); // protect LDS before next stage
    }

    // epilogue: C/D 16x16 layout col=lane&15, row=(lane>>4)*4+reg
    const int colb = n0 + wc * 64 + ml;
    const int rowb = m0 + wr * 64 + (lane >> 4) * 4;
#pragma unroll
    for (int j = 0; j < 4; ++j) {
        const int col = colb + j * 16;
        const float ws = wscale[col];
        const float bs = bias[col];
#pragma unroll
        for (int i = 0; i < 4; ++i) {
            const int row = rowb + i * 16;
            float* cp = C + (size_t)row * N + col;
#pragma unroll
            for (int r = 0; r < 4; ++r) {
                // match ref order: (c * a_scale) * w_scale + bias
                cp[(size_t)r * N] = ((float)acc[i][j][r] * ascale[row + r]) * ws + bs;
            }
        }
    }
}

extern "C" void kernel_launch(void* const* d_in, const int* in_sizes, int n_in,
                              void* d_out, int out_size, void* d_ws, size_t ws_size,
                              hipStream_t stream) {
    const float* x      = (const float*)d_in[0];
    const int*   wq     = (const int*)d_in[1];   // int8 values in int32 storage (harness integer convention)
    const float* wscale = (const float*)d_in[2];
    const float* bias   = (const float*)d_in[3];
    float* out          = (float*)d_out;

    const int N = in_sizes[2];
    const int K = in_sizes[1] / N;
    const int M = in_sizes[0] / K;

    // workspace layout: x_q [M*K] i8 | Bt [N*K] i8 | a_scale [M] f32  (~50.4 MB)
    char* ws = (char*)d_ws;
    signed char* xq = (signed char*)ws;
    signed char* bt = (signed char*)(ws + (size_t)M * K);
    float* ascale   = (float*)(ws + (size_t)M * K + (size_t)N * K);

    quant_kernel<<<M, 256, 0, stream>>>(x, xq, ascale, K);
    transpose_pack_kernel<<<dim3(N / 64, K / 64), 256, 0, stream>>>(wq, bt, K, N);
    gemm_i8_kernel<<<dim3(N / TILE_BN, M / TILE_BM), 256, 0, stream>>>(
        xq, bt, ascale, wscale, bias, out, M, N, K);
}